// Round 13
// baseline (225.577 us; speedup 1.0000x reference)
//
#include <hip/hip_runtime.h>

#define D 128
#define B_LOG 6            // 64 rows per bucket
#define ROWS_PB 64
#define MAX_NB 2048        // supports N <= 131072
#define GEMM_GRID 784      // gemm block-range: 1563 tiles -> 2/block
#define CHUNK_LOG 13       // partition chunk = 8192 edges
#define CAP 2560           // LDS record capacity (mean 2047, +11 sigma)

typedef short bf16x8 __attribute__((ext_vector_type(8)));
typedef float f32x4  __attribute__((ext_vector_type(4)));

// round-to-nearest-even float -> bf16 bits
static __device__ __forceinline__ unsigned short f2bf(float f) {
    unsigned u = __float_as_uint(f);
    u += 0x7FFFu + ((u >> 16) & 1u);
    return (unsigned short)(u >> 16);
}

// ---------------------------------------------------------------------------
// Wt[mat][n][k] = bf16(Wmat[k][n]); also zeroes bhist (folds the memset).
// ---------------------------------------------------------------------------
__global__ __launch_bounds__(256) void wconv_kernel(
    const float* __restrict__ W, const float* __restrict__ Ws,
    short* __restrict__ Wt, int* __restrict__ bhist, int nb)
{
    const int idx = blockIdx.x * 256 + threadIdx.x;
    if (idx < 2 * D * D) {
        const int mat = idx >> 14;
        const int rem = idx & (D * D - 1);
        const int n = rem >> 7, k = rem & (D - 1);
        const float* src = mat ? Ws : W;
        Wt[idx] = (short)f2bf(src[k * D + n]);
    }
    if (idx < nb) bhist[idx] = 0;
}

// ---------------------------------------------------------------------------
// Bucket histogram (standalone; only needs rows). LDS-staged merge.
// ---------------------------------------------------------------------------
__global__ __launch_bounds__(256) void bhist_kernel(
    const int* __restrict__ rows, int* __restrict__ bhist, int E, int nb)
{
    __shared__ int h[MAX_NB];
    const int t = threadIdx.x;
    for (int i = t; i < nb; i += 256) h[i] = 0;
    __syncthreads();

    int i = blockIdx.x * 256 + t;
    const int stride = gridDim.x * 256;
    for (; i < E; i += stride) atomicAdd(&h[rows[i] >> B_LOG], 1);
    __syncthreads();

    for (int i2 = t; i2 < nb; i2 += 256) {
        const int c = h[i2];
        if (c) atomicAdd(&bhist[i2], c);
    }
}

// ---------------------------------------------------------------------------
// Exclusive scan over nb bucket counts -> bptr[0..nb], bcur copy.
// 8 elements per thread (nb up to 2048).
// ---------------------------------------------------------------------------
__global__ __launch_bounds__(256) void bscan_kernel(
    const int* __restrict__ bhist, int* __restrict__ bptr,
    int* __restrict__ bcur, int nb)
{
    const int t = threadIdx.x;
    const int base_i = t * 8;
    int v[8];
    int s = 0;
#pragma unroll
    for (int k = 0; k < 8; ++k) {
        v[k] = (base_i + k < nb) ? bhist[base_i + k] : 0;
        s += v[k];
    }

    const int lane = t & 63, wv = t >> 6;
    int sc = s;
    for (int o = 1; o < 64; o <<= 1) {
        const int u = __shfl_up(sc, o, 64);
        if (lane >= o) sc += u;
    }
    __shared__ int wsum[4];
    if (lane == 63) wsum[wv] = sc;
    __syncthreads();

    int wbase = 0;
    for (int w2 = 0; w2 < wv; ++w2) wbase += wsum[w2];
    int excl = wbase + (sc - s);
#pragma unroll
    for (int k = 0; k < 8; ++k) {
        if (base_i + k < nb) { bptr[base_i + k] = excl; bcur[base_i + k] = excl; }
        excl += v[k];
    }
    if (t == 255) bptr[nb] = wsum[0] + wsum[1] + wsum[2] + wsum[3];  // == E
}

// ---------------------------------------------------------------------------
// Fused: blocks [0, GEMM_GRID) = MFMA dual GEMM; the rest = edge partition
// (latency/atomic-bound partition hides under the MFMA-bound GEMM).
// GEMM: waves 0-1: s1b = bf16(x@W); waves 2-3: skipb = bf16(x@Ws + b).
// Partition: 8192-edge chunks, LDS hist -> one cursor atomic per nonzero
// bucket -> contiguous per-chunk-per-bucket writes.
// Record: ((row & 63) << 20) | col, weight bits.
// ---------------------------------------------------------------------------
__global__ __launch_bounds__(256) void gemm_part_kernel(
    const float* __restrict__ x, const short* __restrict__ Wt,
    const float* __restrict__ b, unsigned short* __restrict__ s1b,
    unsigned short* __restrict__ skipb, int N,
    const int* __restrict__ rows, const int* __restrict__ cols,
    const float* __restrict__ ew, int* __restrict__ bcur,
    int2* __restrict__ se1, int E, int nb)
{
    __shared__ short sx[64 * D];   // 16 KiB; partition branch aliases as int[]

    const int t = threadIdx.x;

    if (blockIdx.x >= GEMM_GRID) {
        // ---------------- partition branch ----------------
        int* h = (int*)sx;         // nb ints (<= 8 KB) fit in the 16 KB alias
        const int nbl = gridDim.x - GEMM_GRID;
        const int nchunks = (E + (1 << CHUNK_LOG) - 1) >> CHUNK_LOG;

        for (int c = blockIdx.x - GEMM_GRID; c < nchunks; c += nbl) {
            const int ebeg = c << CHUNK_LOG;
            const int eend = min(ebeg + (1 << CHUNK_LOG), E);

            for (int i = t; i < nb; i += 256) h[i] = 0;
            __syncthreads();

            for (int e = ebeg + t; e < eend; e += 256)
                atomicAdd(&h[rows[e] >> B_LOG], 1);
            __syncthreads();

            for (int i = t; i < nb; i += 256) {
                const int cnt = h[i];
                h[i] = cnt ? atomicAdd(&bcur[i], cnt) : 0;
            }
            __syncthreads();

            for (int e = ebeg + t; e < eend; e += 256) {
                const int r    = rows[e];
                const int bkt  = r >> B_LOG;
                const int slot = atomicAdd(&h[bkt], 1);
                se1[slot] = make_int2(((r & (ROWS_PB - 1)) << 20) | cols[e],
                                      __float_as_int(ew[e]));
            }
            __syncthreads();
        }
        return;
    }

    // ---------------- MFMA dual GEMM branch ----------------
    const int lane = t & 63;
    const int w    = t >> 6;

    const int bmat = w >> 1;
    const int bn0  = (w & 1) * 64 + (lane & 15);
    const int bk0  = (lane >> 4) * 8;
    bf16x8 Bf[4][4];   // [nf][ks]
#pragma unroll
    for (int nf = 0; nf < 4; ++nf)
#pragma unroll
        for (int ks = 0; ks < 4; ++ks)
            Bf[nf][ks] = *(const bf16x8*)&Wt[
                ((size_t)bmat * D + bn0 + nf * 16) * D + ks * 32 + bk0];

    float bias[4];
#pragma unroll
    for (int nf = 0; nf < 4; ++nf)
        bias[nf] = (w >= 2) ? b[(w - 2) * 64 + nf * 16 + (lane & 15)] : 0.f;

    const int ntiles = (N + 63) >> 6;
    const int trow = t >> 2;
    const int tk   = (t & 3) * 4;

    for (int rt = blockIdx.x; rt < ntiles; rt += GEMM_GRID) {
        const int r0 = rt << 6;
        __syncthreads();

        const int grow = min(r0 + trow, N - 1);
        const float* xrow = &x[(size_t)grow * D];
#pragma unroll
        for (int i = 0; i < 8; ++i) {
            const int k = tk + i * 16;
            const float4 v = *(const float4*)&xrow[k];
            const unsigned lo = (unsigned)f2bf(v.x) | ((unsigned)f2bf(v.y) << 16);
            const unsigned hi = (unsigned)f2bf(v.z) | ((unsigned)f2bf(v.w) << 16);
            unsigned byte = trow * 256 + k * 2;
            byte ^= (unsigned)((trow & 7) << 4);
            *(uint2*)((char*)sx + byte) = make_uint2(lo, hi);
        }
        __syncthreads();

        f32x4 acc[4][4];
#pragma unroll
        for (int mf = 0; mf < 4; ++mf)
#pragma unroll
            for (int nf = 0; nf < 4; ++nf)
                acc[mf][nf] = (f32x4){0.f, 0.f, 0.f, 0.f};

#pragma unroll
        for (int ks = 0; ks < 4; ++ks) {
            bf16x8 Af[4];
#pragma unroll
            for (int mf = 0; mf < 4; ++mf) {
                const int row = mf * 16 + (lane & 15);
                unsigned byte = row * 256 + (ks * 32 + bk0) * 2;
                byte ^= (unsigned)((row & 7) << 4);
                Af[mf] = *(const bf16x8*)((const char*)sx + byte);
            }
#pragma unroll
            for (int mf = 0; mf < 4; ++mf)
#pragma unroll
                for (int nf = 0; nf < 4; ++nf)
                    acc[mf][nf] = __builtin_amdgcn_mfma_f32_16x16x32_bf16(
                        Af[mf], Bf[nf][ks], acc[mf][nf], 0, 0, 0);
        }

#pragma unroll
        for (int mf = 0; mf < 4; ++mf) {
#pragma unroll
            for (int i = 0; i < 4; ++i) {
                const int row = r0 + mf * 16 + (lane >> 4) * 4 + i;
                if (row < N) {
                    if (w < 2) {
#pragma unroll
                        for (int nf = 0; nf < 4; ++nf) {
                            const int col = w * 64 + nf * 16 + (lane & 15);
                            s1b[(size_t)row * D + col] = f2bf(acc[mf][nf][i]);
                        }
                    } else {
#pragma unroll
                        for (int nf = 0; nf < 4; ++nf) {
                            const int col = (w - 2) * 64 + nf * 16 + (lane & 15);
                            skipb[(size_t)row * D + col] =
                                f2bf(acc[mf][nf][i] + bias[nf]);
                        }
                    }
                }
            }
        }
    }
}

// ---------------------------------------------------------------------------
// Fused counting-sort + SpMM. Block (512 thr) = one 64-row bucket.
// Pass 1: count rows (se1 read sequentially). Pass 2: scan-64 -> place full
// 8B records into LDS in row order (second se1 read L2-hot, ~16 KB range).
// Pass 3: wave wv owns rows [wv*8, wv*8+8): 8-deep LDS-broadcast edge reads,
// coalesced s1b gathers, out[r] = agg + skipb[r] (pure write).
// Overflow (> CAP): in-block fallback (skip init + wave-per-edge atomics;
// bucket rows are block-exclusive).
// ---------------------------------------------------------------------------
__global__ __launch_bounds__(512) void sortspmm_kernel(
    const unsigned short* __restrict__ s1b,
    const unsigned short* __restrict__ skipb,
    const int* __restrict__ bptr, const int2* __restrict__ se1,
    float* __restrict__ out, int N)
{
    __shared__ long long recs[CAP];     // 20.5 KiB
    __shared__ int rpos[ROWS_PB];       // row start
    __shared__ int rcur[ROWS_PB];       // counter / cursor (final = row end)

    const int t    = threadIdx.x;
    const int lane = t & 63;
    const int wv   = t >> 6;            // 0..7
    const int bk   = blockIdx.x;
    const int r0   = bk << B_LOG;
    const int j    = lane * 2;

    const int beg  = bptr[bk];
    const int end  = bptr[bk + 1];
    const int cntE = end - beg;
    const long long* seq = (const long long*)se1;

    if (t < ROWS_PB) rcur[t] = 0;
    __syncthreads();

    // pass 1: per-row counts
    for (int e = beg + t; e < end; e += 512)
        atomicAdd(&rcur[(unsigned)se1[e].x >> 20], 1);
    __syncthreads();

    // scan-64 (inclusive Hillis-Steele over 64 entries, then exclusive)
    if (t < ROWS_PB) rpos[t] = rcur[t];
    __syncthreads();
#pragma unroll
    for (int off = 1; off < ROWS_PB; off <<= 1) {
        int v = (t < ROWS_PB && t >= off) ? rpos[t - off] : 0;
        __syncthreads();
        if (t < ROWS_PB) rpos[t] += v;
        __syncthreads();
    }
    if (t < ROWS_PB) {
        const int excl = rpos[t] - rcur[t];
        rpos[t] = excl;
        rcur[t] = excl;
    }
    __syncthreads();

    if (cntE <= CAP) {
        // pass 2: place records into LDS in row order
        for (int e = beg + t; e < end; e += 512) {
            const long long rec = seq[e];
            const int rl = (int)((unsigned)rec >> 20);
            const int slot = atomicAdd(&rcur[rl], 1);
            recs[slot] = rec;
        }
        __syncthreads();

        // pass 3: spmm, wave per row (8 rows per wave)
        for (int i = 0; i < 8; ++i) {
            const int rr = wv * 8 + i;
            const int r  = r0 + rr;
            if (r >= N) break;
            int p        = rpos[rr];
            const int pe = rcur[rr];    // final cursor == row end

            float2 acc = make_float2(0.f, 0.f);
            for (; p + 8 <= pe; p += 8) {
                long long ed[8];
#pragma unroll
                for (int k = 0; k < 8; ++k) ed[k] = recs[p + k];
                unsigned pk[8];
#pragma unroll
                for (int k = 0; k < 8; ++k)
                    pk[k] = *(const unsigned*)&s1b[
                        (size_t)((unsigned)ed[k] & 0xFFFFFu) * D + j];
#pragma unroll
                for (int k = 0; k < 8; ++k) {
                    const float w = __int_as_float((int)(ed[k] >> 32));
                    acc.x = fmaf(w, __uint_as_float(pk[k] << 16), acc.x);
                    acc.y = fmaf(w, __uint_as_float(pk[k] & 0xFFFF0000u), acc.y);
                }
            }
            for (; p < pe; ++p) {
                const long long ed = recs[p];
                const unsigned pk = *(const unsigned*)&s1b[
                    (size_t)((unsigned)ed & 0xFFFFFu) * D + j];
                const float w = __int_as_float((int)(ed >> 32));
                acc.x = fmaf(w, __uint_as_float(pk << 16), acc.x);
                acc.y = fmaf(w, __uint_as_float(pk & 0xFFFF0000u), acc.y);
            }

            const unsigned sk = *(const unsigned*)&skipb[(size_t)r * D + j];
            float2 o;
            o.x = acc.x + __uint_as_float(sk << 16);
            o.y = acc.y + __uint_as_float(sk & 0xFFFF0000u);
            *(float2*)&out[(size_t)r * D + j] = o;
        }
    } else {
        // overflow fallback: init rows with skip, then wave-per-edge atomics
        const int nr = min(ROWS_PB, N - r0);
        for (int idx = t; idx < nr * 64; idx += 512) {
            const int rr = idx >> 6;
            const int cc = (idx & 63) * 2;
            const unsigned sk = *(const unsigned*)&skipb[(size_t)(r0 + rr) * D + cc];
            *(float2*)&out[(size_t)(r0 + rr) * D + cc] =
                make_float2(__uint_as_float(sk << 16),
                            __uint_as_float(sk & 0xFFFF0000u));
        }
        __syncthreads();

        for (int e = beg + wv; e < end; e += 8) {
            const long long ed = seq[e];
            const unsigned key = (unsigned)ed;
            const int rl = (int)(key >> 20);
            const float w = __int_as_float((int)(ed >> 32));
            const unsigned pk = *(const unsigned*)&s1b[
                (size_t)(key & 0xFFFFFu) * D + j];
            float* op = &out[(size_t)(r0 + rl) * D + j];
            unsafeAtomicAdd(op,     w * __uint_as_float(pk << 16));
            unsafeAtomicAdd(op + 1, w * __uint_as_float(pk & 0xFFFF0000u));
        }
    }
}

// ---------------------------------------------------------------------------
// Fallback vector dual GEMM (ws too small): fp32 math, bf16 s1 store,
// fp32 out init (used with the atomic spmm_edges fallback).
// ---------------------------------------------------------------------------
__global__ __launch_bounds__(512) void dual_gemm_fb_kernel(
    const float* __restrict__ x, const float* __restrict__ W,
    const float* __restrict__ Ws, const float* __restrict__ b,
    unsigned short* __restrict__ s1b, float* __restrict__ out, int N)
{
    __shared__ float sW[D * D];
    __shared__ float sWs[D * D];

    const int t = threadIdx.x;
    for (int i = t * 4; i < D * D; i += 512 * 4) {
        *(float4*)&sW[i]  = *(const float4*)&W[i];
        *(float4*)&sWs[i] = *(const float4*)&Ws[i];
    }
    __syncthreads();

    const int lane   = t & 63;
    const int wave   = blockIdx.x * 8 + (t >> 6);
    const int nwaves = gridDim.x * 8;
    const int j      = lane * 2;
    const float2 bb  = *(const float2*)&b[j];

    for (int r0 = wave * 4; r0 < N; r0 += nwaves * 4) {
        float2 xr[4];
#pragma unroll
        for (int r = 0; r < 4; ++r)
            xr[r] = *(const float2*)&x[(size_t)(r0 + r) * D + j];

        float2 a1[4], a2[4];
#pragma unroll
        for (int r = 0; r < 4; ++r) {
            a1[r] = make_float2(0.f, 0.f);
            a2[r] = make_float2(0.f, 0.f);
        }

#pragma unroll 8
        for (int k = 0; k < D; ++k) {
            const float2 wk  = *(const float2*)&sW[k * D + j];
            const float2 wsk = *(const float2*)&sWs[k * D + j];
#pragma unroll
            for (int r = 0; r < 4; ++r) {
                const float xv = __shfl((k & 1) ? xr[r].y : xr[r].x, k >> 1, 64);
                a1[r].x = fmaf(xv, wk.x,  a1[r].x);
                a1[r].y = fmaf(xv, wk.y,  a1[r].y);
                a2[r].x = fmaf(xv, wsk.x, a2[r].x);
                a2[r].y = fmaf(xv, wsk.y, a2[r].y);
            }
        }

#pragma unroll
        for (int r = 0; r < 4; ++r) {
            const unsigned pk = (unsigned)f2bf(a1[r].x) |
                                ((unsigned)f2bf(a1[r].y) << 16);
            *(unsigned*)&s1b[(size_t)(r0 + r) * D + j] = pk;
            *(float2*)&out[(size_t)(r0 + r) * D + j] =
                make_float2(a2[r].x + bb.x, a2[r].y + bb.y);
        }
    }
}

// ---------------------------------------------------------------------------
// Fallback: edge-parallel atomic scatter (bf16 s1).
// ---------------------------------------------------------------------------
__global__ __launch_bounds__(256) void spmm_edges_kernel(
    const unsigned short* __restrict__ s1b, const int* __restrict__ rows,
    const int* __restrict__ cols, const float* __restrict__ ew,
    float* __restrict__ out, int E)
{
    const int lane = threadIdx.x & 63;
    const int wave = blockIdx.x * (blockDim.x >> 6) + (threadIdx.x >> 6);
    const int nw   = gridDim.x * (blockDim.x >> 6);
    const int j    = lane * 2;

    const int epw   = (E + nw - 1) / nw;
    const int e_beg = wave * epw;
    const int e_end = min(e_beg + epw, E);

    for (int e = e_beg; e < e_end; ++e) {
        const int   r = rows[e];
        const int   c = cols[e];
        const float w = ew[e];
        const unsigned p = *(const unsigned*)&s1b[(size_t)c * D + j];
        float* o = &out[(size_t)r * D + j];
        unsafeAtomicAdd(o,     w * __uint_as_float(p << 16));
        unsafeAtomicAdd(o + 1, w * __uint_as_float(p & 0xFFFF0000u));
    }
}

// ---------------------------------------------------------------------------
extern "C" void kernel_launch(void* const* d_in, const int* in_sizes, int n_in,
                              void* d_out, int out_size, void* d_ws, size_t ws_size,
                              hipStream_t stream) {
    const float* x    = (const float*)d_in[0];
    const int*   rows = (const int*)  d_in[1];
    const int*   cols = (const int*)  d_in[2];
    const float* ew   = (const float*)d_in[3];
    const float* W    = (const float*)d_in[4];
    const float* Ws   = (const float*)d_in[5];
    const float* b    = (const float*)d_in[6];
    float*       out  = (float*)d_out;

    const int N  = in_sizes[0] / D;
    const int E  = in_sizes[1];
    const int nb = (N + ROWS_PB - 1) >> B_LOG;

    // Workspace: s1b (N*D bf16) | skipb (N*D bf16) | Wt (2*D*D bf16) |
    //            bhist nb | bptr nb+1 | bcur nb | pad | se1 E int2
    const size_t s1_bytes   = ((size_t)N * D * 2 + 15) & ~(size_t)15;
    const size_t skip_bytes = s1_bytes;
    const size_t wt_bytes   = (size_t)2 * D * D * 2;
    const size_t int_bytes  = (((size_t)(3 * nb + 1)) * 4 + 7) & ~(size_t)7;
    const size_t need       = s1_bytes + skip_bytes + wt_bytes + int_bytes
                              + (size_t)E * 8;

    unsigned short* s1b = (unsigned short*)d_ws;

    if (ws_size >= need && nb <= MAX_NB) {
        unsigned short* skipb = (unsigned short*)((char*)d_ws + s1_bytes);
        short* Wt    = (short*)((char*)d_ws + s1_bytes + skip_bytes);
        int*   ibase = (int*)((char*)d_ws + s1_bytes + skip_bytes + wt_bytes);
        int*  bhist  = ibase;                       // nb
        int*  bptr   = ibase + nb;                  // nb+1
        int*  bcur   = ibase + 2 * nb + 1;          // nb
        int2* se1    = (int2*)((char*)d_ws + s1_bytes + skip_bytes + wt_bytes
                               + int_bytes);

        wconv_kernel<<<(2 * D * D + 255) / 256, 256, 0, stream>>>(W, Ws, Wt, bhist, nb);
        bhist_kernel<<<512, 256, 0, stream>>>(rows, bhist, E, nb);
        bscan_kernel<<<1, 256, 0, stream>>>(bhist, bptr, bcur, nb);

        const int nchunks = (E + (1 << CHUNK_LOG) - 1) >> CHUNK_LOG;
        const int part_blocks = min(nchunks, 1024);
        gemm_part_kernel<<<GEMM_GRID + part_blocks, 256, 0, stream>>>(
            x, Wt, b, s1b, skipb, N, rows, cols, ew, bcur, se1, E, nb);

        sortspmm_kernel<<<nb, 512, 0, stream>>>(s1b, skipb, bptr, se1, out, N);
    } else {
        dual_gemm_fb_kernel<<<768, 512, 0, stream>>>(x, W, Ws, b, s1b, (float*)d_out, N);
        spmm_edges_kernel<<<2048, 256, 0, stream>>>(s1b, rows, cols, ew, (float*)d_out, E);
    }
}

// Round 14
// 225.431 us; speedup vs baseline: 1.0006x; 1.0006x over previous
//
#include <hip/hip_runtime.h>

#define D 128
#define B_LOG 6            // 64 rows per bucket
#define ROWS_PB 64
#define MAX_NB 2048        // supports N <= 131072
#define GEMM_GRID 784      // gemm block-range: 1563 tiles -> 2/block
#define CHUNK_LOG 12       // partition chunk = 4096 edges (782 chunks -> TLP)
#define CAP 2560           // LDS record capacity (mean 2047, +11 sigma)

typedef short bf16x8 __attribute__((ext_vector_type(8)));
typedef float f32x4  __attribute__((ext_vector_type(4)));

// round-to-nearest-even float -> bf16 bits
static __device__ __forceinline__ unsigned short f2bf(float f) {
    unsigned u = __float_as_uint(f);
    u += 0x7FFFu + ((u >> 16) & 1u);
    return (unsigned short)(u >> 16);
}

// ---------------------------------------------------------------------------
// Wt[mat][n][k] = bf16(Wmat[k][n]); also zeroes bhist (folds the memset).
// ---------------------------------------------------------------------------
__global__ __launch_bounds__(256) void wconv_kernel(
    const float* __restrict__ W, const float* __restrict__ Ws,
    short* __restrict__ Wt, int* __restrict__ bhist, int nb)
{
    const int idx = blockIdx.x * 256 + threadIdx.x;
    if (idx < 2 * D * D) {
        const int mat = idx >> 14;
        const int rem = idx & (D * D - 1);
        const int n = rem >> 7, k = rem & (D - 1);
        const float* src = mat ? Ws : W;
        Wt[idx] = (short)f2bf(src[k * D + n]);
    }
    if (idx < nb) bhist[idx] = 0;
}

// ---------------------------------------------------------------------------
// Bucket histogram (standalone; only needs rows). LDS-staged merge.
// ---------------------------------------------------------------------------
__global__ __launch_bounds__(256) void bhist_kernel(
    const int* __restrict__ rows, int* __restrict__ bhist, int E, int nb)
{
    __shared__ int h[MAX_NB];
    const int t = threadIdx.x;
    for (int i = t; i < nb; i += 256) h[i] = 0;
    __syncthreads();

    int i = blockIdx.x * 256 + t;
    const int stride = gridDim.x * 256;
    for (; i < E; i += stride) atomicAdd(&h[rows[i] >> B_LOG], 1);
    __syncthreads();

    for (int i2 = t; i2 < nb; i2 += 256) {
        const int c = h[i2];
        if (c) atomicAdd(&bhist[i2], c);
    }
}

// ---------------------------------------------------------------------------
// Exclusive scan over nb bucket counts -> bptr[0..nb], bcur copy.
// 8 elements per thread (nb up to 2048).
// ---------------------------------------------------------------------------
__global__ __launch_bounds__(256) void bscan_kernel(
    const int* __restrict__ bhist, int* __restrict__ bptr,
    int* __restrict__ bcur, int nb)
{
    const int t = threadIdx.x;
    const int base_i = t * 8;
    int v[8];
    int s = 0;
#pragma unroll
    for (int k = 0; k < 8; ++k) {
        v[k] = (base_i + k < nb) ? bhist[base_i + k] : 0;
        s += v[k];
    }

    const int lane = t & 63, wv = t >> 6;
    int sc = s;
    for (int o = 1; o < 64; o <<= 1) {
        const int u = __shfl_up(sc, o, 64);
        if (lane >= o) sc += u;
    }
    __shared__ int wsum[4];
    if (lane == 63) wsum[wv] = sc;
    __syncthreads();

    int wbase = 0;
    for (int w2 = 0; w2 < wv; ++w2) wbase += wsum[w2];
    int excl = wbase + (sc - s);
#pragma unroll
    for (int k = 0; k < 8; ++k) {
        if (base_i + k < nb) { bptr[base_i + k] = excl; bcur[base_i + k] = excl; }
        excl += v[k];
    }
    if (t == 255) bptr[nb] = wsum[0] + wsum[1] + wsum[2] + wsum[3];  // == E
}

// ---------------------------------------------------------------------------
// Fused: blocks [0, GEMM_GRID) = MFMA dual GEMM; the rest = edge partition.
// Partition is PER-BLOCK latency-bound (serial edge loops with LDS-atomic
// slot assignment) -> needs many blocks: 4096-edge chunks give 782 partition
// blocks so it hides under the GEMM (r13 lesson: 8192-chunks halved blocks
// and doubled partition wall time).
// GEMM: waves 0-1: s1b = bf16(x@W); waves 2-3: skipb = bf16(x@Ws + b).
// Record: ((row & 63) << 20) | col, weight bits.
// ---------------------------------------------------------------------------
__global__ __launch_bounds__(256) void gemm_part_kernel(
    const float* __restrict__ x, const short* __restrict__ Wt,
    const float* __restrict__ b, unsigned short* __restrict__ s1b,
    unsigned short* __restrict__ skipb, int N,
    const int* __restrict__ rows, const int* __restrict__ cols,
    const float* __restrict__ ew, int* __restrict__ bcur,
    int2* __restrict__ se1, int E, int nb)
{
    __shared__ short sx[64 * D];   // 16 KiB; partition branch aliases as int[]

    const int t = threadIdx.x;

    if (blockIdx.x >= GEMM_GRID) {
        // ---------------- partition branch ----------------
        int* h = (int*)sx;         // nb ints (<= 8 KB) fit in the 16 KB alias
        const int nbl = gridDim.x - GEMM_GRID;
        const int nchunks = (E + (1 << CHUNK_LOG) - 1) >> CHUNK_LOG;

        for (int c = blockIdx.x - GEMM_GRID; c < nchunks; c += nbl) {
            const int ebeg = c << CHUNK_LOG;
            const int eend = min(ebeg + (1 << CHUNK_LOG), E);

            for (int i = t; i < nb; i += 256) h[i] = 0;
            __syncthreads();

            for (int e = ebeg + t; e < eend; e += 256)
                atomicAdd(&h[rows[e] >> B_LOG], 1);
            __syncthreads();

            for (int i = t; i < nb; i += 256) {
                const int cnt = h[i];
                h[i] = cnt ? atomicAdd(&bcur[i], cnt) : 0;
            }
            __syncthreads();

            for (int e = ebeg + t; e < eend; e += 256) {
                const int r    = rows[e];
                const int bkt  = r >> B_LOG;
                const int slot = atomicAdd(&h[bkt], 1);
                se1[slot] = make_int2(((r & (ROWS_PB - 1)) << 20) | cols[e],
                                      __float_as_int(ew[e]));
            }
            __syncthreads();
        }
        return;
    }

    // ---------------- MFMA dual GEMM branch ----------------
    const int lane = t & 63;
    const int w    = t >> 6;

    const int bmat = w >> 1;
    const int bn0  = (w & 1) * 64 + (lane & 15);
    const int bk0  = (lane >> 4) * 8;
    bf16x8 Bf[4][4];   // [nf][ks]
#pragma unroll
    for (int nf = 0; nf < 4; ++nf)
#pragma unroll
        for (int ks = 0; ks < 4; ++ks)
            Bf[nf][ks] = *(const bf16x8*)&Wt[
                ((size_t)bmat * D + bn0 + nf * 16) * D + ks * 32 + bk0];

    float bias[4];
#pragma unroll
    for (int nf = 0; nf < 4; ++nf)
        bias[nf] = (w >= 2) ? b[(w - 2) * 64 + nf * 16 + (lane & 15)] : 0.f;

    const int ntiles = (N + 63) >> 6;
    const int trow = t >> 2;
    const int tk   = (t & 3) * 4;

    for (int rt = blockIdx.x; rt < ntiles; rt += GEMM_GRID) {
        const int r0 = rt << 6;
        __syncthreads();

        const int grow = min(r0 + trow, N - 1);
        const float* xrow = &x[(size_t)grow * D];
#pragma unroll
        for (int i = 0; i < 8; ++i) {
            const int k = tk + i * 16;
            const float4 v = *(const float4*)&xrow[k];
            const unsigned lo = (unsigned)f2bf(v.x) | ((unsigned)f2bf(v.y) << 16);
            const unsigned hi = (unsigned)f2bf(v.z) | ((unsigned)f2bf(v.w) << 16);
            unsigned byte = trow * 256 + k * 2;
            byte ^= (unsigned)((trow & 7) << 4);
            *(uint2*)((char*)sx + byte) = make_uint2(lo, hi);
        }
        __syncthreads();

        f32x4 acc[4][4];
#pragma unroll
        for (int mf = 0; mf < 4; ++mf)
#pragma unroll
            for (int nf = 0; nf < 4; ++nf)
                acc[mf][nf] = (f32x4){0.f, 0.f, 0.f, 0.f};

#pragma unroll
        for (int ks = 0; ks < 4; ++ks) {
            bf16x8 Af[4];
#pragma unroll
            for (int mf = 0; mf < 4; ++mf) {
                const int row = mf * 16 + (lane & 15);
                unsigned byte = row * 256 + (ks * 32 + bk0) * 2;
                byte ^= (unsigned)((row & 7) << 4);
                Af[mf] = *(const bf16x8*)((const char*)sx + byte);
            }
#pragma unroll
            for (int mf = 0; mf < 4; ++mf)
#pragma unroll
                for (int nf = 0; nf < 4; ++nf)
                    acc[mf][nf] = __builtin_amdgcn_mfma_f32_16x16x32_bf16(
                        Af[mf], Bf[nf][ks], acc[mf][nf], 0, 0, 0);
        }

#pragma unroll
        for (int mf = 0; mf < 4; ++mf) {
#pragma unroll
            for (int i = 0; i < 4; ++i) {
                const int row = r0 + mf * 16 + (lane >> 4) * 4 + i;
                if (row < N) {
                    if (w < 2) {
#pragma unroll
                        for (int nf = 0; nf < 4; ++nf) {
                            const int col = w * 64 + nf * 16 + (lane & 15);
                            s1b[(size_t)row * D + col] = f2bf(acc[mf][nf][i]);
                        }
                    } else {
#pragma unroll
                        for (int nf = 0; nf < 4; ++nf) {
                            const int col = (w - 2) * 64 + nf * 16 + (lane & 15);
                            skipb[(size_t)row * D + col] =
                                f2bf(acc[mf][nf][i] + bias[nf]);
                        }
                    }
                }
            }
        }
    }
}

// ---------------------------------------------------------------------------
// Fused counting-sort + SpMM. Block (512 thr) = one 64-row bucket.
// Pass 1: count rows (se1 read sequentially). Pass 2: scan-64 -> place full
// 8B records into LDS in row order (second se1 read L2-hot, ~16 KB range).
// Pass 3: wave wv owns rows [wv*8, wv*8+8): 8-deep LDS-broadcast edge reads,
// coalesced s1b gathers, out[r] = agg + skipb[r] (pure write).
// Overflow (> CAP): in-block fallback (skip init + wave-per-edge atomics;
// bucket rows are block-exclusive).
// ---------------------------------------------------------------------------
__global__ __launch_bounds__(512) void sortspmm_kernel(
    const unsigned short* __restrict__ s1b,
    const unsigned short* __restrict__ skipb,
    const int* __restrict__ bptr, const int2* __restrict__ se1,
    float* __restrict__ out, int N)
{
    __shared__ long long recs[CAP];     // 20.5 KiB
    __shared__ int rpos[ROWS_PB];       // row start
    __shared__ int rcur[ROWS_PB];       // counter / cursor (final = row end)

    const int t    = threadIdx.x;
    const int lane = t & 63;
    const int wv   = t >> 6;            // 0..7
    const int bk   = blockIdx.x;
    const int r0   = bk << B_LOG;
    const int j    = lane * 2;

    const int beg  = bptr[bk];
    const int end  = bptr[bk + 1];
    const int cntE = end - beg;
    const long long* seq = (const long long*)se1;

    if (t < ROWS_PB) rcur[t] = 0;
    __syncthreads();

    // pass 1: per-row counts
    for (int e = beg + t; e < end; e += 512)
        atomicAdd(&rcur[(unsigned)se1[e].x >> 20], 1);
    __syncthreads();

    // scan-64 (inclusive Hillis-Steele over 64 entries, then exclusive)
    if (t < ROWS_PB) rpos[t] = rcur[t];
    __syncthreads();
#pragma unroll
    for (int off = 1; off < ROWS_PB; off <<= 1) {
        int v = (t < ROWS_PB && t >= off) ? rpos[t - off] : 0;
        __syncthreads();
        if (t < ROWS_PB) rpos[t] += v;
        __syncthreads();
    }
    if (t < ROWS_PB) {
        const int excl = rpos[t] - rcur[t];
        rpos[t] = excl;
        rcur[t] = excl;
    }
    __syncthreads();

    if (cntE <= CAP) {
        // pass 2: place records into LDS in row order
        for (int e = beg + t; e < end; e += 512) {
            const long long rec = seq[e];
            const int rl = (int)((unsigned)rec >> 20);
            const int slot = atomicAdd(&rcur[rl], 1);
            recs[slot] = rec;
        }
        __syncthreads();

        // pass 3: spmm, wave per row (8 rows per wave)
        for (int i = 0; i < 8; ++i) {
            const int rr = wv * 8 + i;
            const int r  = r0 + rr;
            if (r >= N) break;
            int p        = rpos[rr];
            const int pe = rcur[rr];    // final cursor == row end

            float2 acc = make_float2(0.f, 0.f);
            for (; p + 8 <= pe; p += 8) {
                long long ed[8];
#pragma unroll
                for (int k = 0; k < 8; ++k) ed[k] = recs[p + k];
                unsigned pk[8];
#pragma unroll
                for (int k = 0; k < 8; ++k)
                    pk[k] = *(const unsigned*)&s1b[
                        (size_t)((unsigned)ed[k] & 0xFFFFFu) * D + j];
#pragma unroll
                for (int k = 0; k < 8; ++k) {
                    const float w = __int_as_float((int)(ed[k] >> 32));
                    acc.x = fmaf(w, __uint_as_float(pk[k] << 16), acc.x);
                    acc.y = fmaf(w, __uint_as_float(pk[k] & 0xFFFF0000u), acc.y);
                }
            }
            for (; p < pe; ++p) {
                const long long ed = recs[p];
                const unsigned pk = *(const unsigned*)&s1b[
                    (size_t)((unsigned)ed & 0xFFFFFu) * D + j];
                const float w = __int_as_float((int)(ed >> 32));
                acc.x = fmaf(w, __uint_as_float(pk << 16), acc.x);
                acc.y = fmaf(w, __uint_as_float(pk & 0xFFFF0000u), acc.y);
            }

            const unsigned sk = *(const unsigned*)&skipb[(size_t)r * D + j];
            float2 o;
            o.x = acc.x + __uint_as_float(sk << 16);
            o.y = acc.y + __uint_as_float(sk & 0xFFFF0000u);
            *(float2*)&out[(size_t)r * D + j] = o;
        }
    } else {
        // overflow fallback: init rows with skip, then wave-per-edge atomics
        const int nr = min(ROWS_PB, N - r0);
        for (int idx = t; idx < nr * 64; idx += 512) {
            const int rr = idx >> 6;
            const int cc = (idx & 63) * 2;
            const unsigned sk = *(const unsigned*)&skipb[(size_t)(r0 + rr) * D + cc];
            *(float2*)&out[(size_t)(r0 + rr) * D + cc] =
                make_float2(__uint_as_float(sk << 16),
                            __uint_as_float(sk & 0xFFFF0000u));
        }
        __syncthreads();

        for (int e = beg + wv; e < end; e += 8) {
            const long long ed = seq[e];
            const unsigned key = (unsigned)ed;
            const int rl = (int)(key >> 20);
            const float w = __int_as_float((int)(ed >> 32));
            const unsigned pk = *(const unsigned*)&s1b[
                (size_t)(key & 0xFFFFFu) * D + j];
            float* op = &out[(size_t)(r0 + rl) * D + j];
            unsafeAtomicAdd(op,     w * __uint_as_float(pk << 16));
            unsafeAtomicAdd(op + 1, w * __uint_as_float(pk & 0xFFFF0000u));
        }
    }
}

// ---------------------------------------------------------------------------
// Fallback vector dual GEMM (ws too small): fp32 math, bf16 s1 store,
// fp32 out init (used with the atomic spmm_edges fallback).
// ---------------------------------------------------------------------------
__global__ __launch_bounds__(512) void dual_gemm_fb_kernel(
    const float* __restrict__ x, const float* __restrict__ W,
    const float* __restrict__ Ws, const float* __restrict__ b,
    unsigned short* __restrict__ s1b, float* __restrict__ out, int N)
{
    __shared__ float sW[D * D];
    __shared__ float sWs[D * D];

    const int t = threadIdx.x;
    for (int i = t * 4; i < D * D; i += 512 * 4) {
        *(float4*)&sW[i]  = *(const float4*)&W[i];
        *(float4*)&sWs[i] = *(const float4*)&Ws[i];
    }
    __syncthreads();

    const int lane   = t & 63;
    const int wave   = blockIdx.x * 8 + (t >> 6);
    const int nwaves = gridDim.x * 8;
    const int j      = lane * 2;
    const float2 bb  = *(const float2*)&b[j];

    for (int r0 = wave * 4; r0 < N; r0 += nwaves * 4) {
        float2 xr[4];
#pragma unroll
        for (int r = 0; r < 4; ++r)
            xr[r] = *(const float2*)&x[(size_t)(r0 + r) * D + j];

        float2 a1[4], a2[4];
#pragma unroll
        for (int r = 0; r < 4; ++r) {
            a1[r] = make_float2(0.f, 0.f);
            a2[r] = make_float2(0.f, 0.f);
        }

#pragma unroll 8
        for (int k = 0; k < D; ++k) {
            const float2 wk  = *(const float2*)&sW[k * D + j];
            const float2 wsk = *(const float2*)&sWs[k * D + j];
#pragma unroll
            for (int r = 0; r < 4; ++r) {
                const float xv = __shfl((k & 1) ? xr[r].y : xr[r].x, k >> 1, 64);
                a1[r].x = fmaf(xv, wk.x,  a1[r].x);
                a1[r].y = fmaf(xv, wk.y,  a1[r].y);
                a2[r].x = fmaf(xv, wsk.x, a2[r].x);
                a2[r].y = fmaf(xv, wsk.y, a2[r].y);
            }
        }

#pragma unroll
        for (int r = 0; r < 4; ++r) {
            const unsigned pk = (unsigned)f2bf(a1[r].x) |
                                ((unsigned)f2bf(a1[r].y) << 16);
            *(unsigned*)&s1b[(size_t)(r0 + r) * D + j] = pk;
            *(float2*)&out[(size_t)(r0 + r) * D + j] =
                make_float2(a2[r].x + bb.x, a2[r].y + bb.y);
        }
    }
}

// ---------------------------------------------------------------------------
// Fallback: edge-parallel atomic scatter (bf16 s1).
// ---------------------------------------------------------------------------
__global__ __launch_bounds__(256) void spmm_edges_kernel(
    const unsigned short* __restrict__ s1b, const int* __restrict__ rows,
    const int* __restrict__ cols, const float* __restrict__ ew,
    float* __restrict__ out, int E)
{
    const int lane = threadIdx.x & 63;
    const int wave = blockIdx.x * (blockDim.x >> 6) + (threadIdx.x >> 6);
    const int nw   = gridDim.x * (blockDim.x >> 6);
    const int j    = lane * 2;

    const int epw   = (E + nw - 1) / nw;
    const int e_beg = wave * epw;
    const int e_end = min(e_beg + epw, E);

    for (int e = e_beg; e < e_end; ++e) {
        const int   r = rows[e];
        const int   c = cols[e];
        const float w = ew[e];
        const unsigned p = *(const unsigned*)&s1b[(size_t)c * D + j];
        float* o = &out[(size_t)r * D + j];
        unsafeAtomicAdd(o,     w * __uint_as_float(p << 16));
        unsafeAtomicAdd(o + 1, w * __uint_as_float(p & 0xFFFF0000u));
    }
}

// ---------------------------------------------------------------------------
extern "C" void kernel_launch(void* const* d_in, const int* in_sizes, int n_in,
                              void* d_out, int out_size, void* d_ws, size_t ws_size,
                              hipStream_t stream) {
    const float* x    = (const float*)d_in[0];
    const int*   rows = (const int*)  d_in[1];
    const int*   cols = (const int*)  d_in[2];
    const float* ew   = (const float*)d_in[3];
    const float* W    = (const float*)d_in[4];
    const float* Ws   = (const float*)d_in[5];
    const float* b    = (const float*)d_in[6];
    float*       out  = (float*)d_out;

    const int N  = in_sizes[0] / D;
    const int E  = in_sizes[1];
    const int nb = (N + ROWS_PB - 1) >> B_LOG;

    // Workspace: s1b (N*D bf16) | skipb (N*D bf16) | Wt (2*D*D bf16) |
    //            bhist nb | bptr nb+1 | bcur nb | pad | se1 E int2
    const size_t s1_bytes   = ((size_t)N * D * 2 + 15) & ~(size_t)15;
    const size_t skip_bytes = s1_bytes;
    const size_t wt_bytes   = (size_t)2 * D * D * 2;
    const size_t int_bytes  = (((size_t)(3 * nb + 1)) * 4 + 7) & ~(size_t)7;
    const size_t need       = s1_bytes + skip_bytes + wt_bytes + int_bytes
                              + (size_t)E * 8;

    unsigned short* s1b = (unsigned short*)d_ws;

    if (ws_size >= need && nb <= MAX_NB) {
        unsigned short* skipb = (unsigned short*)((char*)d_ws + s1_bytes);
        short* Wt    = (short*)((char*)d_ws + s1_bytes + skip_bytes);
        int*   ibase = (int*)((char*)d_ws + s1_bytes + skip_bytes + wt_bytes);
        int*  bhist  = ibase;                       // nb
        int*  bptr   = ibase + nb;                  // nb+1
        int*  bcur   = ibase + 2 * nb + 1;          // nb
        int2* se1    = (int2*)((char*)d_ws + s1_bytes + skip_bytes + wt_bytes
                               + int_bytes);

        wconv_kernel<<<(2 * D * D + 255) / 256, 256, 0, stream>>>(W, Ws, Wt, bhist, nb);
        bhist_kernel<<<512, 256, 0, stream>>>(rows, bhist, E, nb);
        bscan_kernel<<<1, 256, 0, stream>>>(bhist, bptr, bcur, nb);

        const int nchunks = (E + (1 << CHUNK_LOG) - 1) >> CHUNK_LOG;
        const int part_blocks = min(nchunks, 1024);
        gemm_part_kernel<<<GEMM_GRID + part_blocks, 256, 0, stream>>>(
            x, Wt, b, s1b, skipb, N, rows, cols, ew, bcur, se1, E, nb);

        sortspmm_kernel<<<nb, 512, 0, stream>>>(s1b, skipb, bptr, se1, out, N);
    } else {
        dual_gemm_fb_kernel<<<768, 512, 0, stream>>>(x, W, Ws, b, s1b, (float*)d_out, N);
        spmm_edges_kernel<<<2048, 256, 0, stream>>>(s1b, rows, cols, ew, (float*)d_out, E);
    }
}

// Round 15
// 219.656 us; speedup vs baseline: 1.0270x; 1.0263x over previous
//
#include <hip/hip_runtime.h>

#define D 128
#define BP_LOG 7           // partition bucket = 128 rows (nb=782: long runs)
#define ROWS_H 64          // sortspmm half-bucket = 64 rows (small LDS: occ)
#define MAX_NB 1024        // partition buckets; supports N <= 131072
#define GEMM_GRID 784      // gemm block-range: 1563 tiles -> 2/block
#define CHUNK_LOG 12       // partition chunk = 4096 edges
#define CAP 2560           // LDS record capacity per half (mean 2047, +11ated)

typedef short bf16x8 __attribute__((ext_vector_type(8)));
typedef float f32x4  __attribute__((ext_vector_type(4)));

// round-to-nearest-even float -> bf16 bits
static __device__ __forceinline__ unsigned short f2bf(float f) {
    unsigned u = __float_as_uint(f);
    u += 0x7FFFu + ((u >> 16) & 1u);
    return (unsigned short)(u >> 16);
}

// ---------------------------------------------------------------------------
// Wt[mat][n][k] = bf16(Wmat[k][n]); also zeroes bhist (folds the memset).
// ---------------------------------------------------------------------------
__global__ __launch_bounds__(256) void wconv_kernel(
    const float* __restrict__ W, const float* __restrict__ Ws,
    short* __restrict__ Wt, int* __restrict__ bhist, int nb)
{
    const int idx = blockIdx.x * 256 + threadIdx.x;
    if (idx < 2 * D * D) {
        const int mat = idx >> 14;
        const int rem = idx & (D * D - 1);
        const int n = rem >> 7, k = rem & (D - 1);
        const float* src = mat ? Ws : W;
        Wt[idx] = (short)f2bf(src[k * D + n]);
    }
    if (idx < nb) bhist[idx] = 0;
}

// ---------------------------------------------------------------------------
// Bucket histogram over 128-row buckets. LDS-staged merge.
// ---------------------------------------------------------------------------
__global__ __launch_bounds__(256) void bhist_kernel(
    const int* __restrict__ rows, int* __restrict__ bhist, int E, int nb)
{
    __shared__ int h[MAX_NB];
    const int t = threadIdx.x;
    for (int i = t; i < nb; i += 256) h[i] = 0;
    __syncthreads();

    int i = blockIdx.x * 256 + t;
    const int stride = gridDim.x * 256;
    for (; i < E; i += stride) atomicAdd(&h[rows[i] >> BP_LOG], 1);
    __syncthreads();

    for (int i2 = t; i2 < nb; i2 += 256) {
        const int c = h[i2];
        if (c) atomicAdd(&bhist[i2], c);
    }
}

// ---------------------------------------------------------------------------
// Exclusive scan over nb bucket counts -> bptr[0..nb], bcur copy.
// ---------------------------------------------------------------------------
__global__ __launch_bounds__(256) void bscan_kernel(
    const int* __restrict__ bhist, int* __restrict__ bptr,
    int* __restrict__ bcur, int nb)
{
    const int t = threadIdx.x;
    const int base_i = t * 4;
    int v[4];
    int s = 0;
#pragma unroll
    for (int k = 0; k < 4; ++k) {
        v[k] = (base_i + k < nb) ? bhist[base_i + k] : 0;
        s += v[k];
    }

    const int lane = t & 63, wv = t >> 6;
    int sc = s;
    for (int o = 1; o < 64; o <<= 1) {
        const int u = __shfl_up(sc, o, 64);
        if (lane >= o) sc += u;
    }
    __shared__ int wsum[4];
    if (lane == 63) wsum[wv] = sc;
    __syncthreads();

    int wbase = 0;
    for (int w2 = 0; w2 < wv; ++w2) wbase += wsum[w2];
    int excl = wbase + (sc - s);
#pragma unroll
    for (int k = 0; k < 4; ++k) {
        if (base_i + k < nb) { bptr[base_i + k] = excl; bcur[base_i + k] = excl; }
        excl += v[k];
    }
    if (t == 255) bptr[nb] = wsum[0] + wsum[1] + wsum[2] + wsum[3];  // == E
}

// ---------------------------------------------------------------------------
// Fused: blocks [0, GEMM_GRID) = MFMA dual GEMM; the rest = edge partition
// into 128-row buckets (782 -> 5.2-edge mean runs, the proven-fast config;
// r14 lesson: 64-row partition buckets doubled partition wall time).
// GEMM: waves 0-1: s1b = bf16(x@W); waves 2-3: skipb = bf16(x@Ws + b).
// Record: ((row & 127) << 20) | col, weight bits.
// ---------------------------------------------------------------------------
__global__ __launch_bounds__(256) void gemm_part_kernel(
    const float* __restrict__ x, const short* __restrict__ Wt,
    const float* __restrict__ b, unsigned short* __restrict__ s1b,
    unsigned short* __restrict__ skipb, int N,
    const int* __restrict__ rows, const int* __restrict__ cols,
    const float* __restrict__ ew, int* __restrict__ bcur,
    int2* __restrict__ se1, int E, int nb)
{
    __shared__ short sx[64 * D];   // 16 KiB; partition branch aliases as int[]

    const int t = threadIdx.x;

    if (blockIdx.x >= GEMM_GRID) {
        // ---------------- partition branch ----------------
        int* h = (int*)sx;
        const int nbl = gridDim.x - GEMM_GRID;
        const int nchunks = (E + (1 << CHUNK_LOG) - 1) >> CHUNK_LOG;

        for (int c = blockIdx.x - GEMM_GRID; c < nchunks; c += nbl) {
            const int ebeg = c << CHUNK_LOG;
            const int eend = min(ebeg + (1 << CHUNK_LOG), E);

            for (int i = t; i < nb; i += 256) h[i] = 0;
            __syncthreads();

            for (int e = ebeg + t; e < eend; e += 256)
                atomicAdd(&h[rows[e] >> BP_LOG], 1);
            __syncthreads();

            for (int i = t; i < nb; i += 256) {
                const int cnt = h[i];
                h[i] = cnt ? atomicAdd(&bcur[i], cnt) : 0;
            }
            __syncthreads();

            for (int e = ebeg + t; e < eend; e += 256) {
                const int r    = rows[e];
                const int bkt  = r >> BP_LOG;
                const int slot = atomicAdd(&h[bkt], 1);
                se1[slot] = make_int2(((r & 127) << 20) | cols[e],
                                      __float_as_int(ew[e]));
            }
            __syncthreads();
        }
        return;
    }

    // ---------------- MFMA dual GEMM branch ----------------
    const int lane = t & 63;
    const int w    = t >> 6;

    const int bmat = w >> 1;
    const int bn0  = (w & 1) * 64 + (lane & 15);
    const int bk0  = (lane >> 4) * 8;
    bf16x8 Bf[4][4];   // [nf][ks]
#pragma unroll
    for (int nf = 0; nf < 4; ++nf)
#pragma unroll
        for (int ks = 0; ks < 4; ++ks)
            Bf[nf][ks] = *(const bf16x8*)&Wt[
                ((size_t)bmat * D + bn0 + nf * 16) * D + ks * 32 + bk0];

    float bias[4];
#pragma unroll
    for (int nf = 0; nf < 4; ++nf)
        bias[nf] = (w >= 2) ? b[(w - 2) * 64 + nf * 16 + (lane & 15)] : 0.f;

    const int ntiles = (N + 63) >> 6;
    const int trow = t >> 2;
    const int tk   = (t & 3) * 4;

    for (int rt = blockIdx.x; rt < ntiles; rt += GEMM_GRID) {
        const int r0 = rt << 6;
        __syncthreads();

        const int grow = min(r0 + trow, N - 1);
        const float* xrow = &x[(size_t)grow * D];
#pragma unroll
        for (int i = 0; i < 8; ++i) {
            const int k = tk + i * 16;
            const float4 v = *(const float4*)&xrow[k];
            const unsigned lo = (unsigned)f2bf(v.x) | ((unsigned)f2bf(v.y) << 16);
            const unsigned hi = (unsigned)f2bf(v.z) | ((unsigned)f2bf(v.w) << 16);
            unsigned byte = trow * 256 + k * 2;
            byte ^= (unsigned)((trow & 7) << 4);
            *(uint2*)((char*)sx + byte) = make_uint2(lo, hi);
        }
        __syncthreads();

        f32x4 acc[4][4];
#pragma unroll
        for (int mf = 0; mf < 4; ++mf)
#pragma unroll
            for (int nf = 0; nf < 4; ++nf)
                acc[mf][nf] = (f32x4){0.f, 0.f, 0.f, 0.f};

#pragma unroll
        for (int ks = 0; ks < 4; ++ks) {
            bf16x8 Af[4];
#pragma unroll
            for (int mf = 0; mf < 4; ++mf) {
                const int row = mf * 16 + (lane & 15);
                unsigned byte = row * 256 + (ks * 32 + bk0) * 2;
                byte ^= (unsigned)((row & 7) << 4);
                Af[mf] = *(const bf16x8*)((const char*)sx + byte);
            }
#pragma unroll
            for (int mf = 0; mf < 4; ++mf)
#pragma unroll
                for (int nf = 0; nf < 4; ++nf)
                    acc[mf][nf] = __builtin_amdgcn_mfma_f32_16x16x32_bf16(
                        Af[mf], Bf[nf][ks], acc[mf][nf], 0, 0, 0);
        }

#pragma unroll
        for (int mf = 0; mf < 4; ++mf) {
#pragma unroll
            for (int i = 0; i < 4; ++i) {
                const int row = r0 + mf * 16 + (lane >> 4) * 4 + i;
                if (row < N) {
                    if (w < 2) {
#pragma unroll
                        for (int nf = 0; nf < 4; ++nf) {
                            const int col = w * 64 + nf * 16 + (lane & 15);
                            s1b[(size_t)row * D + col] = f2bf(acc[mf][nf][i]);
                        }
                    } else {
#pragma unroll
                        for (int nf = 0; nf < 4; ++nf) {
                            const int col = (w - 2) * 64 + nf * 16 + (lane & 15);
                            skipb[(size_t)row * D + col] =
                                f2bf(acc[mf][nf][i] + bias[nf]);
                        }
                    }
                }
            }
        }
    }
}

// ---------------------------------------------------------------------------
// Fused counting-sort + SpMM. Block (512 thr) = one 64-row HALF of a
// 128-row partition bucket (sb = bk>>1, h = bk&1). Scans the super-bucket
// range filtering (rl>>6)==h; places matching 8B records into LDS in row
// order (adjacent half-blocks co-resident -> second scan L2-hot). Pass 3:
// wave wv owns rows [wv*8, wv*8+8): 8-deep LDS-broadcast edge reads,
// coalesced s1b gathers, out[r] = agg + skipb[r] (pure write).
// Small LDS (20.5 KB) keeps 4 blocks/CU resident (the r13 occupancy win).
// Overflow (> CAP): in-block filtered fallback (rows are block-exclusive).
// ---------------------------------------------------------------------------
__global__ __launch_bounds__(512) void sortspmm_kernel(
    const unsigned short* __restrict__ s1b,
    const unsigned short* __restrict__ skipb,
    const int* __restrict__ bptr, const int2* __restrict__ se1,
    float* __restrict__ out, int N)
{
    __shared__ long long recs[CAP];     // 20.5 KiB
    __shared__ int rpos[ROWS_H];        // row start
    __shared__ int rcur[ROWS_H];        // counter / cursor (final = row end)
    __shared__ int hcnt_s;

    const int t    = threadIdx.x;
    const int lane = t & 63;
    const int wv   = t >> 6;            // 0..7
    const int sb   = blockIdx.x >> 1;   // super-bucket
    const int hh   = blockIdx.x & 1;    // half
    const int r0   = (sb << BP_LOG) + (hh << 6);
    const int j    = lane * 2;

    const int beg  = bptr[sb];
    const int end  = bptr[sb + 1];
    const long long* seq = (const long long*)se1;

    if (t < ROWS_H) rcur[t] = 0;
    __syncthreads();

    // pass 1: per-row counts for this half
    for (int e = beg + t; e < end; e += 512) {
        const int rl = (int)((unsigned)se1[e].x >> 20);
        if ((rl >> 6) == hh) atomicAdd(&rcur[rl & 63], 1);
    }
    __syncthreads();

    // wave-0 shuffle scan over the 64 counts -> exclusive starts
    if (t < ROWS_H) {
        const int v = rcur[t];
        int sc = v;
#pragma unroll
        for (int o = 1; o < 64; o <<= 1) {
            const int u = __shfl_up(sc, o, 64);
            if (lane >= o) sc += u;
        }
        rpos[t] = sc - v;
        rcur[t] = sc - v;
        if (t == 63) hcnt_s = sc;
    }
    __syncthreads();
    const int hcnt = hcnt_s;

    if (hcnt <= CAP) {
        // pass 2: place this half's records into LDS in row order
        for (int e = beg + t; e < end; e += 512) {
            const long long rec = seq[e];
            const int rl = (int)((unsigned)rec >> 20);
            if ((rl >> 6) == hh) {
                const int slot = atomicAdd(&rcur[rl & 63], 1);
                recs[slot] = rec;
            }
        }
        __syncthreads();

        // pass 3: spmm, wave per row (8 rows per wave)
        for (int i = 0; i < 8; ++i) {
            const int rr = wv * 8 + i;
            const int r  = r0 + rr;
            if (r >= N) break;
            int p        = rpos[rr];
            const int pe = rcur[rr];    // final cursor == row end

            float2 acc = make_float2(0.f, 0.f);
            for (; p + 8 <= pe; p += 8) {
                long long ed[8];
#pragma unroll
                for (int k = 0; k < 8; ++k) ed[k] = recs[p + k];
                unsigned pk[8];
#pragma unroll
                for (int k = 0; k < 8; ++k)
                    pk[k] = *(const unsigned*)&s1b[
                        (size_t)((unsigned)ed[k] & 0xFFFFFu) * D + j];
#pragma unroll
                for (int k = 0; k < 8; ++k) {
                    const float w = __int_as_float((int)(ed[k] >> 32));
                    acc.x = fmaf(w, __uint_as_float(pk[k] << 16), acc.x);
                    acc.y = fmaf(w, __uint_as_float(pk[k] & 0xFFFF0000u), acc.y);
                }
            }
            for (; p < pe; ++p) {
                const long long ed = recs[p];
                const unsigned pk = *(const unsigned*)&s1b[
                    (size_t)((unsigned)ed & 0xFFFFFu) * D + j];
                const float w = __int_as_float((int)(ed >> 32));
                acc.x = fmaf(w, __uint_as_float(pk << 16), acc.x);
                acc.y = fmaf(w, __uint_as_float(pk & 0xFFFF0000u), acc.y);
            }

            const unsigned sk = *(const unsigned*)&skipb[(size_t)r * D + j];
            float2 o;
            o.x = acc.x + __uint_as_float(sk << 16);
            o.y = acc.y + __uint_as_float(sk & 0xFFFF0000u);
            *(float2*)&out[(size_t)r * D + j] = o;
        }
    } else {
        // overflow fallback: init rows with skip, then filtered atomics
        const int nr = min(ROWS_H, N - r0);
        for (int idx = t; idx < nr * 64; idx += 512) {
            const int rr = idx >> 6;
            const int cc = (idx & 63) * 2;
            const unsigned sk = *(const unsigned*)&skipb[(size_t)(r0 + rr) * D + cc];
            *(float2*)&out[(size_t)(r0 + rr) * D + cc] =
                make_float2(__uint_as_float(sk << 16),
                            __uint_as_float(sk & 0xFFFF0000u));
        }
        __syncthreads();

        for (int e = beg + wv; e < end; e += 8) {
            const long long ed = seq[e];
            const unsigned key = (unsigned)ed;
            const int rl = (int)(key >> 20);
            if ((rl >> 6) != hh) continue;
            const float w = __int_as_float((int)(ed >> 32));
            const unsigned pk = *(const unsigned*)&s1b[
                (size_t)(key & 0xFFFFFu) * D + j];
            float* op = &out[(size_t)(r0 + (rl & 63)) * D + j];
            unsafeAtomicAdd(op,     w * __uint_as_float(pk << 16));
            unsafeAtomicAdd(op + 1, w * __uint_as_float(pk & 0xFFFF0000u));
        }
    }
}

// ---------------------------------------------------------------------------
// Fallback vector dual GEMM (ws too small): fp32 math, bf16 s1 store,
// fp32 out init (used with the atomic spmm_edges fallback).
// ---------------------------------------------------------------------------
__global__ __launch_bounds__(512) void dual_gemm_fb_kernel(
    const float* __restrict__ x, const float* __restrict__ W,
    const float* __restrict__ Ws, const float* __restrict__ b,
    unsigned short* __restrict__ s1b, float* __restrict__ out, int N)
{
    __shared__ float sW[D * D];
    __shared__ float sWs[D * D];

    const int t = threadIdx.x;
    for (int i = t * 4; i < D * D; i += 512 * 4) {
        *(float4*)&sW[i]  = *(const float4*)&W[i];
        *(float4*)&sWs[i] = *(const float4*)&Ws[i];
    }
    __syncthreads();

    const int lane   = t & 63;
    const int wave   = blockIdx.x * 8 + (t >> 6);
    const int nwaves = gridDim.x * 8;
    const int j      = lane * 2;
    const float2 bb  = *(const float2*)&b[j];

    for (int r0 = wave * 4; r0 < N; r0 += nwaves * 4) {
        float2 xr[4];
#pragma unroll
        for (int r = 0; r < 4; ++r)
            xr[r] = *(const float2*)&x[(size_t)(r0 + r) * D + j];

        float2 a1[4], a2[4];
#pragma unroll
        for (int r = 0; r < 4; ++r) {
            a1[r] = make_float2(0.f, 0.f);
            a2[r] = make_float2(0.f, 0.f);
        }

#pragma unroll 8
        for (int k = 0; k < D; ++k) {
            const float2 wk  = *(const float2*)&sW[k * D + j];
            const float2 wsk = *(const float2*)&sWs[k * D + j];
#pragma unroll
            for (int r = 0; r < 4; ++r) {
                const float xv = __shfl((k & 1) ? xr[r].y : xr[r].x, k >> 1, 64);
                a1[r].x = fmaf(xv, wk.x,  a1[r].x);
                a1[r].y = fmaf(xv, wk.y,  a1[r].y);
                a2[r].x = fmaf(xv, wsk.x, a2[r].x);
                a2[r].y = fmaf(xv, wsk.y, a2[r].y);
            }
        }

#pragma unroll
        for (int r = 0; r < 4; ++r) {
            const unsigned pk = (unsigned)f2bf(a1[r].x) |
                                ((unsigned)f2bf(a1[r].y) << 16);
            *(unsigned*)&s1b[(size_t)(r0 + r) * D + j] = pk;
            *(float2*)&out[(size_t)(r0 + r) * D + j] =
                make_float2(a2[r].x + bb.x, a2[r].y + bb.y);
        }
    }
}

// ---------------------------------------------------------------------------
// Fallback: edge-parallel atomic scatter (bf16 s1).
// ---------------------------------------------------------------------------
__global__ __launch_bounds__(256) void spmm_edges_kernel(
    const unsigned short* __restrict__ s1b, const int* __restrict__ rows,
    const int* __restrict__ cols, const float* __restrict__ ew,
    float* __restrict__ out, int E)
{
    const int lane = threadIdx.x & 63;
    const int wave = blockIdx.x * (blockDim.x >> 6) + (threadIdx.x >> 6);
    const int nw   = gridDim.x * (blockDim.x >> 6);
    const int j    = lane * 2;

    const int epw   = (E + nw - 1) / nw;
    const int e_beg = wave * epw;
    const int e_end = min(e_beg + epw, E);

    for (int e = e_beg; e < e_end; ++e) {
        const int   r = rows[e];
        const int   c = cols[e];
        const float w = ew[e];
        const unsigned p = *(const unsigned*)&s1b[(size_t)c * D + j];
        float* o = &out[(size_t)r * D + j];
        unsafeAtomicAdd(o,     w * __uint_as_float(p << 16));
        unsafeAtomicAdd(o + 1, w * __uint_as_float(p & 0xFFFF0000u));
    }
}

// ---------------------------------------------------------------------------
extern "C" void kernel_launch(void* const* d_in, const int* in_sizes, int n_in,
                              void* d_out, int out_size, void* d_ws, size_t ws_size,
                              hipStream_t stream) {
    const float* x    = (const float*)d_in[0];
    const int*   rows = (const int*)  d_in[1];
    const int*   cols = (const int*)  d_in[2];
    const float* ew   = (const float*)d_in[3];
    const float* W    = (const float*)d_in[4];
    const float* Ws   = (const float*)d_in[5];
    const float* b    = (const float*)d_in[6];
    float*       out  = (float*)d_out;

    const int N  = in_sizes[0] / D;
    const int E  = in_sizes[1];
    const int nb = (N + 127) >> BP_LOG;   // 128-row partition buckets

    // Workspace: s1b (N*D bf16) | skipb (N*D bf16) | Wt (2*D*D bf16) |
    //            bhist nb | bptr nb+1 | bcur nb | pad | se1 E int2
    const size_t s1_bytes   = ((size_t)N * D * 2 + 15) & ~(size_t)15;
    const size_t skip_bytes = s1_bytes;
    const size_t wt_bytes   = (size_t)2 * D * D * 2;
    const size_t int_bytes  = (((size_t)(3 * nb + 1)) * 4 + 7) & ~(size_t)7;
    const size_t need       = s1_bytes + skip_bytes + wt_bytes + int_bytes
                              + (size_t)E * 8;

    unsigned short* s1b = (unsigned short*)d_ws;

    if (ws_size >= need && nb <= MAX_NB) {
        unsigned short* skipb = (unsigned short*)((char*)d_ws + s1_bytes);
        short* Wt    = (short*)((char*)d_ws + s1_bytes + skip_bytes);
        int*   ibase = (int*)((char*)d_ws + s1_bytes + skip_bytes + wt_bytes);
        int*  bhist  = ibase;                       // nb
        int*  bptr   = ibase + nb;                  // nb+1
        int*  bcur   = ibase + 2 * nb + 1;          // nb
        int2* se1    = (int2*)((char*)d_ws + s1_bytes + skip_bytes + wt_bytes
                               + int_bytes);

        wconv_kernel<<<(2 * D * D + 255) / 256, 256, 0, stream>>>(W, Ws, Wt, bhist, nb);
        bhist_kernel<<<512, 256, 0, stream>>>(rows, bhist, E, nb);
        bscan_kernel<<<1, 256, 0, stream>>>(bhist, bptr, bcur, nb);

        const int nchunks = (E + (1 << CHUNK_LOG) - 1) >> CHUNK_LOG;
        const int part_blocks = min(nchunks, 1024);
        gemm_part_kernel<<<GEMM_GRID + part_blocks, 256, 0, stream>>>(
            x, Wt, b, s1b, skipb, N, rows, cols, ew, bcur, se1, E, nb);

        sortspmm_kernel<<<nb * 2, 512, 0, stream>>>(s1b, skipb, bptr, se1, out, N);
    } else {
        dual_gemm_fb_kernel<<<768, 512, 0, stream>>>(x, W, Ws, b, s1b, (float*)d_out, N);
        spmm_edges_kernel<<<2048, 256, 0, stream>>>(s1b, rows, cols, ew, (float*)d_out, E);
    }
}

// Round 16
// 219.481 us; speedup vs baseline: 1.0278x; 1.0008x over previous
//
#include <hip/hip_runtime.h>

#define D 128
#define BP_LOG 7           // partition bucket = 128 rows (nb=782: long runs)
#define ROWS_H 64          // sortspmm half-bucket = 64 rows
#define MAX_NB 1024        // partition buckets; supports N <= 131072
#define GEMM_GRID 784      // gemm block-range: 1563 tiles -> 2/block
#define CHUNK_LOG 12       // partition chunk = 4096 edges
#define CAP 2560           // LDS record capacity per half (mean 2047, +11 sigma)

typedef short bf16x8 __attribute__((ext_vector_type(8)));
typedef float f32x4  __attribute__((ext_vector_type(4)));

// round-to-nearest-even float -> bf16 bits
static __device__ __forceinline__ unsigned short f2bf(float f) {
    unsigned u = __float_as_uint(f);
    u += 0x7FFFu + ((u >> 16) & 1u);
    return (unsigned short)(u >> 16);
}

// ---------------------------------------------------------------------------
// Wt[mat][n][k] = bf16(Wmat[k][n]); also zeroes bhist (folds the memset).
// ---------------------------------------------------------------------------
__global__ __launch_bounds__(256) void wconv_kernel(
    const float* __restrict__ W, const float* __restrict__ Ws,
    short* __restrict__ Wt, int* __restrict__ bhist, int nb)
{
    const int idx = blockIdx.x * 256 + threadIdx.x;
    if (idx < 2 * D * D) {
        const int mat = idx >> 14;
        const int rem = idx & (D * D - 1);
        const int n = rem >> 7, k = rem & (D - 1);
        const float* src = mat ? Ws : W;
        Wt[idx] = (short)f2bf(src[k * D + n]);
    }
    if (idx < nb) bhist[idx] = 0;
}

// ---------------------------------------------------------------------------
// Bucket histogram over 128-row buckets. LDS-staged merge.
// ---------------------------------------------------------------------------
__global__ __launch_bounds__(256) void bhist_kernel(
    const int* __restrict__ rows, int* __restrict__ bhist, int E, int nb)
{
    __shared__ int h[MAX_NB];
    const int t = threadIdx.x;
    for (int i = t; i < nb; i += 256) h[i] = 0;
    __syncthreads();

    int i = blockIdx.x * 256 + t;
    const int stride = gridDim.x * 256;
    for (; i < E; i += stride) atomicAdd(&h[rows[i] >> BP_LOG], 1);
    __syncthreads();

    for (int i2 = t; i2 < nb; i2 += 256) {
        const int c = h[i2];
        if (c) atomicAdd(&bhist[i2], c);
    }
}

// ---------------------------------------------------------------------------
// Exclusive scan over nb bucket counts -> bptr[0..nb], bcur copy.
// ---------------------------------------------------------------------------
__global__ __launch_bounds__(256) void bscan_kernel(
    const int* __restrict__ bhist, int* __restrict__ bptr,
    int* __restrict__ bcur, int nb)
{
    const int t = threadIdx.x;
    const int base_i = t * 4;
    int v[4];
    int s = 0;
#pragma unroll
    for (int k = 0; k < 4; ++k) {
        v[k] = (base_i + k < nb) ? bhist[base_i + k] : 0;
        s += v[k];
    }

    const int lane = t & 63, wv = t >> 6;
    int sc = s;
    for (int o = 1; o < 64; o <<= 1) {
        const int u = __shfl_up(sc, o, 64);
        if (lane >= o) sc += u;
    }
    __shared__ int wsum[4];
    if (lane == 63) wsum[wv] = sc;
    __syncthreads();

    int wbase = 0;
    for (int w2 = 0; w2 < wv; ++w2) wbase += wsum[w2];
    int excl = wbase + (sc - s);
#pragma unroll
    for (int k = 0; k < 4; ++k) {
        if (base_i + k < nb) { bptr[base_i + k] = excl; bcur[base_i + k] = excl; }
        excl += v[k];
    }
    if (t == 255) bptr[nb] = wsum[0] + wsum[1] + wsum[2] + wsum[3];  // == E
}

// ---------------------------------------------------------------------------
// Fused: blocks [0, GEMM_GRID) = MFMA dual GEMM; the rest = edge partition
// into 128-row buckets (782 -> 5.2-edge mean runs, the proven-fast config).
// GEMM: waves 0-1: s1b = bf16(x@W); waves 2-3: skipb = bf16(x@Ws + b).
// Record: ((row & 127) << 20) | col, weight bits.
// ---------------------------------------------------------------------------
__global__ __launch_bounds__(256) void gemm_part_kernel(
    const float* __restrict__ x, const short* __restrict__ Wt,
    const float* __restrict__ b, unsigned short* __restrict__ s1b,
    unsigned short* __restrict__ skipb, int N,
    const int* __restrict__ rows, const int* __restrict__ cols,
    const float* __restrict__ ew, int* __restrict__ bcur,
    int2* __restrict__ se1, int E, int nb)
{
    __shared__ short sx[64 * D];   // 16 KiB; partition branch aliases as int[]

    const int t = threadIdx.x;

    if (blockIdx.x >= GEMM_GRID) {
        // ---------------- partition branch ----------------
        int* h = (int*)sx;
        const int nbl = gridDim.x - GEMM_GRID;
        const int nchunks = (E + (1 << CHUNK_LOG) - 1) >> CHUNK_LOG;

        for (int c = blockIdx.x - GEMM_GRID; c < nchunks; c += nbl) {
            const int ebeg = c << CHUNK_LOG;
            const int eend = min(ebeg + (1 << CHUNK_LOG), E);

            for (int i = t; i < nb; i += 256) h[i] = 0;
            __syncthreads();

            for (int e = ebeg + t; e < eend; e += 256)
                atomicAdd(&h[rows[e] >> BP_LOG], 1);
            __syncthreads();

            for (int i = t; i < nb; i += 256) {
                const int cnt = h[i];
                h[i] = cnt ? atomicAdd(&bcur[i], cnt) : 0;
            }
            __syncthreads();

            for (int e = ebeg + t; e < eend; e += 256) {
                const int r    = rows[e];
                const int bkt  = r >> BP_LOG;
                const int slot = atomicAdd(&h[bkt], 1);
                se1[slot] = make_int2(((r & 127) << 20) | cols[e],
                                      __float_as_int(ew[e]));
            }
            __syncthreads();
        }
        return;
    }

    // ---------------- MFMA dual GEMM branch ----------------
    const int lane = t & 63;
    const int w    = t >> 6;

    const int bmat = w >> 1;
    const int bn0  = (w & 1) * 64 + (lane & 15);
    const int bk0  = (lane >> 4) * 8;
    bf16x8 Bf[4][4];   // [nf][ks]
#pragma unroll
    for (int nf = 0; nf < 4; ++nf)
#pragma unroll
        for (int ks = 0; ks < 4; ++ks)
            Bf[nf][ks] = *(const bf16x8*)&Wt[
                ((size_t)bmat * D + bn0 + nf * 16) * D + ks * 32 + bk0];

    float bias[4];
#pragma unroll
    for (int nf = 0; nf < 4; ++nf)
        bias[nf] = (w >= 2) ? b[(w - 2) * 64 + nf * 16 + (lane & 15)] : 0.f;

    const int ntiles = (N + 63) >> 6;
    const int trow = t >> 2;
    const int tk   = (t & 3) * 4;

    for (int rt = blockIdx.x; rt < ntiles; rt += GEMM_GRID) {
        const int r0 = rt << 6;
        __syncthreads();

        const int grow = min(r0 + trow, N - 1);
        const float* xrow = &x[(size_t)grow * D];
#pragma unroll
        for (int i = 0; i < 8; ++i) {
            const int k = tk + i * 16;
            const float4 v = *(const float4*)&xrow[k];
            const unsigned lo = (unsigned)f2bf(v.x) | ((unsigned)f2bf(v.y) << 16);
            const unsigned hi = (unsigned)f2bf(v.z) | ((unsigned)f2bf(v.w) << 16);
            unsigned byte = trow * 256 + k * 2;
            byte ^= (unsigned)((trow & 7) << 4);
            *(uint2*)((char*)sx + byte) = make_uint2(lo, hi);
        }
        __syncthreads();

        f32x4 acc[4][4];
#pragma unroll
        for (int mf = 0; mf < 4; ++mf)
#pragma unroll
            for (int nf = 0; nf < 4; ++nf)
                acc[mf][nf] = (f32x4){0.f, 0.f, 0.f, 0.f};

#pragma unroll
        for (int ks = 0; ks < 4; ++ks) {
            bf16x8 Af[4];
#pragma unroll
            for (int mf = 0; mf < 4; ++mf) {
                const int row = mf * 16 + (lane & 15);
                unsigned byte = row * 256 + (ks * 32 + bk0) * 2;
                byte ^= (unsigned)((row & 7) << 4);
                Af[mf] = *(const bf16x8*)((const char*)sx + byte);
            }
#pragma unroll
            for (int mf = 0; mf < 4; ++mf)
#pragma unroll
                for (int nf = 0; nf < 4; ++nf)
                    acc[mf][nf] = __builtin_amdgcn_mfma_f32_16x16x32_bf16(
                        Af[mf], Bf[nf][ks], acc[mf][nf], 0, 0, 0);
        }

#pragma unroll
        for (int mf = 0; mf < 4; ++mf) {
#pragma unroll
            for (int i = 0; i < 4; ++i) {
                const int row = r0 + mf * 16 + (lane >> 4) * 4 + i;
                if (row < N) {
                    if (w < 2) {
#pragma unroll
                        for (int nf = 0; nf < 4; ++nf) {
                            const int col = w * 64 + nf * 16 + (lane & 15);
                            s1b[(size_t)row * D + col] = f2bf(acc[mf][nf][i]);
                        }
                    } else {
#pragma unroll
                        for (int nf = 0; nf < 4; ++nf) {
                            const int col = (w - 2) * 64 + nf * 16 + (lane & 15);
                            skipb[(size_t)row * D + col] =
                                f2bf(acc[mf][nf][i] + bias[nf]);
                        }
                    }
                }
            }
        }
    }
}

// ---------------------------------------------------------------------------
// Fused sort + SpMM, SINGLE global scan. Block (512 thr) = one 64-row half
// of a 128-row partition bucket.
// Scan 1 (only): ballot-aggregated append of this half's records into LDS
//   (unsorted; one LDS cursor atomic per wave per iter).
// Then LDS-local: count rows -> wave-0 shuffle scan -> 16-bit permutation.
// Pass 3: wave wv owns rows [wv*8, wv*8+8): 8-deep edge reads via
//   recs[perm[p]] (both broadcast LDS loads), coalesced s1b gathers,
//   out[r] = agg + skipb[r] (pure write).
// Overflow (> CAP appends, ~11-sigma): in-block fallback -- skip init +
// filtered wave-per-edge atomics (bucket rows are block-exclusive).
// ---------------------------------------------------------------------------
__global__ __launch_bounds__(512) void sortspmm_kernel(
    const unsigned short* __restrict__ s1b,
    const unsigned short* __restrict__ skipb,
    const int* __restrict__ bptr, const int2* __restrict__ se1,
    float* __restrict__ out, int N)
{
    __shared__ long long recs[CAP];          // 20 KiB, append order
    __shared__ unsigned short perm[CAP];     // 5 KiB, row-sorted -> append idx
    __shared__ int rpos[ROWS_H];             // row start
    __shared__ int rcur[ROWS_H];             // counter / cursor (final = end)
    __shared__ int nstage;

    const int t    = threadIdx.x;
    const int lane = t & 63;
    const int wv   = t >> 6;            // 0..7
    const int sb   = blockIdx.x >> 1;   // super-bucket
    const int hh   = blockIdx.x & 1;    // half
    const int r0   = (sb << BP_LOG) + (hh << 6);
    const int j    = lane * 2;

    const int beg  = bptr[sb];
    const int end  = bptr[sb + 1];
    const long long* seq = (const long long*)se1;

    if (t < ROWS_H) rcur[t] = 0;
    if (t == 0) nstage = 0;
    __syncthreads();

    // single scan: stage this half's records (unsorted, wave-aggregated)
    for (int e = beg + t; e < end; e += 512) {
        const long long rec = seq[e];
        const int rl = (int)((unsigned)rec >> 20);
        const bool m = ((rl >> 6) == hh);
        const unsigned long long bal = __ballot(m);
        if (bal) {
            const int leader = (int)__ffsll((long long)bal) - 1;
            int base = 0;
            if (lane == leader) base = atomicAdd(&nstage, __popcll(bal));
            base = __shfl(base, leader, 64);
            if (m) {
                const int slot = base +
                    (int)__popcll(bal & ((1ull << lane) - 1ull));
                if (slot < CAP) recs[slot] = rec;
            }
        }
    }
    __syncthreads();
    const int hcnt = nstage;

    if (hcnt <= CAP) {
        // LDS-local: count rows
        for (int i = t; i < hcnt; i += 512)
            atomicAdd(&rcur[(int)((unsigned)recs[i] >> 20) & 63], 1);
        __syncthreads();

        // wave-0 shuffle scan over the 64 counts -> exclusive starts
        if (t < ROWS_H) {
            const int v = rcur[t];
            int sc = v;
#pragma unroll
            for (int o = 1; o < 64; o <<= 1) {
                const int u = __shfl_up(sc, o, 64);
                if (lane >= o) sc += u;
            }
            rpos[t] = sc - v;
            rcur[t] = sc - v;
        }
        __syncthreads();

        // LDS-local: build 16-bit permutation (row-sorted -> append index)
        for (int i = t; i < hcnt; i += 512) {
            const int rl = (int)((unsigned)recs[i] >> 20) & 63;
            perm[atomicAdd(&rcur[rl], 1)] = (unsigned short)i;
        }
        __syncthreads();

        // pass 3: spmm, wave per row (8 rows per wave)
        for (int i2 = 0; i2 < 8; ++i2) {
            const int rr = wv * 8 + i2;
            const int r  = r0 + rr;
            if (r >= N) break;
            int p        = rpos[rr];
            const int pe = rcur[rr];    // final cursor == row end

            float2 acc = make_float2(0.f, 0.f);
            for (; p + 8 <= pe; p += 8) {
                int idx[8];
#pragma unroll
                for (int k = 0; k < 8; ++k) idx[k] = perm[p + k];
                long long ed[8];
#pragma unroll
                for (int k = 0; k < 8; ++k) ed[k] = recs[idx[k]];
                unsigned pk[8];
#pragma unroll
                for (int k = 0; k < 8; ++k)
                    pk[k] = *(const unsigned*)&s1b[
                        (size_t)((unsigned)ed[k] & 0xFFFFFu) * D + j];
#pragma unroll
                for (int k = 0; k < 8; ++k) {
                    const float w = __int_as_float((int)(ed[k] >> 32));
                    acc.x = fmaf(w, __uint_as_float(pk[k] << 16), acc.x);
                    acc.y = fmaf(w, __uint_as_float(pk[k] & 0xFFFF0000u), acc.y);
                }
            }
            for (; p < pe; ++p) {
                const long long ed = recs[perm[p]];
                const unsigned pk = *(const unsigned*)&s1b[
                    (size_t)((unsigned)ed & 0xFFFFFu) * D + j];
                const float w = __int_as_float((int)(ed >> 32));
                acc.x = fmaf(w, __uint_as_float(pk << 16), acc.x);
                acc.y = fmaf(w, __uint_as_float(pk & 0xFFFF0000u), acc.y);
            }

            const unsigned sk = *(const unsigned*)&skipb[(size_t)r * D + j];
            float2 o;
            o.x = acc.x + __uint_as_float(sk << 16);
            o.y = acc.y + __uint_as_float(sk & 0xFFFF0000u);
            *(float2*)&out[(size_t)r * D + j] = o;
        }
    } else {
        // overflow fallback: init rows with skip, then filtered atomics
        const int nr = min(ROWS_H, N - r0);
        for (int idx = t; idx < nr * 64; idx += 512) {
            const int rr = idx >> 6;
            const int cc = (idx & 63) * 2;
            const unsigned sk = *(const unsigned*)&skipb[(size_t)(r0 + rr) * D + cc];
            *(float2*)&out[(size_t)(r0 + rr) * D + cc] =
                make_float2(__uint_as_float(sk << 16),
                            __uint_as_float(sk & 0xFFFF0000u));
        }
        __syncthreads();

        for (int e = beg + wv; e < end; e += 8) {
            const long long ed = seq[e];
            const unsigned key = (unsigned)ed;
            const int rl = (int)(key >> 20);
            if ((rl >> 6) != hh) continue;
            const float w = __int_as_float((int)(ed >> 32));
            const unsigned pk = *(const unsigned*)&s1b[
                (size_t)(key & 0xFFFFFu) * D + j];
            float* op = &out[(size_t)(r0 + (rl & 63)) * D + j];
            unsafeAtomicAdd(op,     w * __uint_as_float(pk << 16));
            unsafeAtomicAdd(op + 1, w * __uint_as_float(pk & 0xFFFF0000u));
        }
    }
}

// ---------------------------------------------------------------------------
// Fallback vector dual GEMM (ws too small): fp32 math, bf16 s1 store,
// fp32 out init (used with the atomic spmm_edges fallback).
// ---------------------------------------------------------------------------
__global__ __launch_bounds__(512) void dual_gemm_fb_kernel(
    const float* __restrict__ x, const float* __restrict__ W,
    const float* __restrict__ Ws, const float* __restrict__ b,
    unsigned short* __restrict__ s1b, float* __restrict__ out, int N)
{
    __shared__ float sW[D * D];
    __shared__ float sWs[D * D];

    const int t = threadIdx.x;
    for (int i = t * 4; i < D * D; i += 512 * 4) {
        *(float4*)&sW[i]  = *(const float4*)&W[i];
        *(float4*)&sWs[i] = *(const float4*)&Ws[i];
    }
    __syncthreads();

    const int lane   = t & 63;
    const int wave   = blockIdx.x * 8 + (t >> 6);
    const int nwaves = gridDim.x * 8;
    const int j      = lane * 2;
    const float2 bb  = *(const float2*)&b[j];

    for (int r0 = wave * 4; r0 < N; r0 += nwaves * 4) {
        float2 xr[4];
#pragma unroll
        for (int r = 0; r < 4; ++r)
            xr[r] = *(const float2*)&x[(size_t)(r0 + r) * D + j];

        float2 a1[4], a2[4];
#pragma unroll
        for (int r = 0; r < 4; ++r) {
            a1[r] = make_float2(0.f, 0.f);
            a2[r] = make_float2(0.f, 0.f);
        }

#pragma unroll 8
        for (int k = 0; k < D; ++k) {
            const float2 wk  = *(const float2*)&sW[k * D + j];
            const float2 wsk = *(const float2*)&sWs[k * D + j];
#pragma unroll
            for (int r = 0; r < 4; ++r) {
                const float xv = __shfl((k & 1) ? xr[r].y : xr[r].x, k >> 1, 64);
                a1[r].x = fmaf(xv, wk.x,  a1[r].x);
                a1[r].y = fmaf(xv, wk.y,  a1[r].y);
                a2[r].x = fmaf(xv, wsk.x, a2[r].x);
                a2[r].y = fmaf(xv, wsk.y, a2[r].y);
            }
        }

#pragma unroll
        for (int r = 0; r < 4; ++r) {
            const unsigned pk = (unsigned)f2bf(a1[r].x) |
                                ((unsigned)f2bf(a1[r].y) << 16);
            *(unsigned*)&s1b[(size_t)(r0 + r) * D + j] = pk;
            *(float2*)&out[(size_t)(r0 + r) * D + j] =
                make_float2(a2[r].x + bb.x, a2[r].y + bb.y);
        }
    }
}

// ---------------------------------------------------------------------------
// Fallback: edge-parallel atomic scatter (bf16 s1).
// ---------------------------------------------------------------------------
__global__ __launch_bounds__(256) void spmm_edges_kernel(
    const unsigned short* __restrict__ s1b, const int* __restrict__ rows,
    const int* __restrict__ cols, const float* __restrict__ ew,
    float* __restrict__ out, int E)
{
    const int lane = threadIdx.x & 63;
    const int wave = blockIdx.x * (blockDim.x >> 6) + (threadIdx.x >> 6);
    const int nw   = gridDim.x * (blockDim.x >> 6);
    const int j    = lane * 2;

    const int epw   = (E + nw - 1) / nw;
    const int e_beg = wave * epw;
    const int e_end = min(e_beg + epw, E);

    for (int e = e_beg; e < e_end; ++e) {
        const int   r = rows[e];
        const int   c = cols[e];
        const float w = ew[e];
        const unsigned p = *(const unsigned*)&s1b[(size_t)c * D + j];
        float* o = &out[(size_t)r * D + j];
        unsafeAtomicAdd(o,     w * __uint_as_float(p << 16));
        unsafeAtomicAdd(o + 1, w * __uint_as_float(p & 0xFFFF0000u));
    }
}

// ---------------------------------------------------------------------------
extern "C" void kernel_launch(void* const* d_in, const int* in_sizes, int n_in,
                              void* d_out, int out_size, void* d_ws, size_t ws_size,
                              hipStream_t stream) {
    const float* x    = (const float*)d_in[0];
    const int*   rows = (const int*)  d_in[1];
    const int*   cols = (const int*)  d_in[2];
    const float* ew   = (const float*)d_in[3];
    const float* W    = (const float*)d_in[4];
    const float* Ws   = (const float*)d_in[5];
    const float* b    = (const float*)d_in[6];
    float*       out  = (float*)d_out;

    const int N  = in_sizes[0] / D;
    const int E  = in_sizes[1];
    const int nb = (N + 127) >> BP_LOG;   // 128-row partition buckets

    // Workspace: s1b (N*D bf16) | skipb (N*D bf16) | Wt (2*D*D bf16) |
    //            bhist nb | bptr nb+1 | bcur nb | pad | se1 E int2
    const size_t s1_bytes   = ((size_t)N * D * 2 + 15) & ~(size_t)15;
    const size_t skip_bytes = s1_bytes;
    const size_t wt_bytes   = (size_t)2 * D * D * 2;
    const size_t int_bytes  = (((size_t)(3 * nb + 1)) * 4 + 7) & ~(size_t)7;
    const size_t need       = s1_bytes + skip_bytes + wt_bytes + int_bytes
                              + (size_t)E * 8;

    unsigned short* s1b = (unsigned short*)d_ws;

    if (ws_size >= need && nb <= MAX_NB) {
        unsigned short* skipb = (unsigned short*)((char*)d_ws + s1_bytes);
        short* Wt    = (short*)((char*)d_ws + s1_bytes + skip_bytes);
        int*   ibase = (int*)((char*)d_ws + s1_bytes + skip_bytes + wt_bytes);
        int*  bhist  = ibase;                       // nb
        int*  bptr   = ibase + nb;                  // nb+1
        int*  bcur   = ibase + 2 * nb + 1;          // nb
        int2* se1    = (int2*)((char*)d_ws + s1_bytes + skip_bytes + wt_bytes
                               + int_bytes);

        wconv_kernel<<<(2 * D * D + 255) / 256, 256, 0, stream>>>(W, Ws, Wt, bhist, nb);
        bhist_kernel<<<512, 256, 0, stream>>>(rows, bhist, E, nb);
        bscan_kernel<<<1, 256, 0, stream>>>(bhist, bptr, bcur, nb);

        const int nchunks = (E + (1 << CHUNK_LOG) - 1) >> CHUNK_LOG;
        const int part_blocks = min(nchunks, 1024);
        gemm_part_kernel<<<GEMM_GRID + part_blocks, 256, 0, stream>>>(
            x, Wt, b, s1b, skipb, N, rows, cols, ew, bcur, se1, E, nb);

        sortspmm_kernel<<<nb * 2, 512, 0, stream>>>(s1b, skipb, bptr, se1, out, N);
    } else {
        dual_gemm_fb_kernel<<<768, 512, 0, stream>>>(x, W, Ws, b, s1b, (float*)d_out, N);
        spmm_edges_kernel<<<2048, 256, 0, stream>>>(s1b, rows, cols, ew, (float*)d_out, E);
    }
}